// Round 2
// baseline (492.182 us; speedup 1.0000x reference)
//
#include <hip/hip_runtime.h>
#include <stdint.h>

#define NN 100000   // nodes
#define NK 10       // sampled neighbors
#define D  256      // hidden dim
#define D2 512      // concat dim
#define MT 32       // nodes per block; 100000/32 = 3125 exactly -> no tails

typedef short bf16x8 __attribute__((ext_vector_type(8)));   // 8 bf16 (4 VGPRs)
typedef float f32x4  __attribute__((ext_vector_type(4)));

__device__ __forceinline__ uint16_t f2bf(float f) {
  uint32_t u = __float_as_uint(f);
  u += 0x7fffu + ((u >> 16) & 1u);   // round-to-nearest-even
  return (uint16_t)(u >> 16);
}
__device__ __forceinline__ uint32_t pack2(float a, float b) {
  return (uint32_t)f2bf(a) | ((uint32_t)f2bf(b) << 16);
}

// async global->LDS, 4 B/lane: lane l reads g+4l, LDS gets base+4l (linear).
// No register destination -> the compiler cannot collapse this pipeline.
__device__ __forceinline__ void gload_lds4(const void* g, void* lds) {
  __builtin_amdgcn_global_load_lds(
      (const __attribute__((address_space(1))) uint32_t*)g,
      (__attribute__((address_space(3))) uint32_t*)lds, 4, 0, 0);
}

// ---------------------------------------------------------------------------
// prep: fused {3x pack_w , quant_x} in one launch.
// blocks [0,192): pack W0/W1/W2 into bf16 MFMA B-fragment order.
// blocks [192, 192+NN/4): int8-quantize x rows (one wave per row).
// ---------------------------------------------------------------------------
__global__ __launch_bounds__(256) void prep(
    const float* __restrict__ x, uint8_t* __restrict__ q8, float* __restrict__ qs,
    const float* __restrict__ W0, const float* __restrict__ W1,
    const float* __restrict__ W2, uint16_t* __restrict__ Wp0,
    uint16_t* __restrict__ Wp1, uint16_t* __restrict__ Wp2)
{
  const int bid = blockIdx.x;
  if (bid < 192) {
    const float* W;
    uint16_t* Wp;
    if (bid < 64)       { W = W0; Wp = Wp0; }
    else if (bid < 128) { W = W1; Wp = Wp1; }
    else                { W = W2; Wp = Wp2; }
    int idx   = ((bid & 63) << 8) + threadIdx.x;   // 0..16383
    int lane  = idx & 63;
    int ntile = (idx >> 6) & 15;
    int kstep = idx >> 10;
    int n  = ntile * 16 + (lane & 15);
    int k0 = kstep * 32 + (lane >> 4) * 8;
    float v[8];
#pragma unroll
    for (int j = 0; j < 8; j++) v[j] = W[(size_t)(k0 + j) * D + n];
    uint4 o;
    o.x = pack2(v[0], v[1]);
    o.y = pack2(v[2], v[3]);
    o.z = pack2(v[4], v[5]);
    o.w = pack2(v[6], v[7]);
    ((uint4*)Wp)[idx] = o;
  } else {
    int node = (bid - 192) * 4 + (threadIdx.x >> 6);
    int lane = threadIdx.x & 63;
    const float4 v = *(const float4*)(x + (size_t)node * D + lane * 4);
    float m = fmaxf(fmaxf(fabsf(v.x), fabsf(v.y)), fmaxf(fabsf(v.z), fabsf(v.w)));
#pragma unroll
    for (int d = 1; d < 64; d <<= 1) m = fmaxf(m, __shfl_xor(m, d, 64));
    float inv = m > 1e-30f ? 127.0f / m : 0.0f;
    int q0 = (int)rintf(v.x * inv), q1 = (int)rintf(v.y * inv);
    int q2 = (int)rintf(v.z * inv), q3 = (int)rintf(v.w * inv);
    uint32_t p = (uint32_t)(q0 & 0xff) | ((uint32_t)(q1 & 0xff) << 8) |
                 ((uint32_t)(q2 & 0xff) << 16) | ((uint32_t)(q3 & 0xff) << 24);
    ((uint32_t*)(q8 + (size_t)node * D))[lane] = p;
    if (lane == 0) qs[node] = m * (1.0f / 127.0f);
  }
}

// ---------------------------------------------------------------------------
// Fused SAGE layer, v3: ASYNC gather via global_load_lds.
//  - wave w owns tile rows 8w..8w+7. adj (80 idx) + row scales prefetched
//    into regs at wave start (2+2 loads), broadcast via __shfl at use.
//  - each neighbor row (256 B int8) is ONE global_load_lds_dword:
//    per-lane global src qtab[nb*256+4l], wave-uniform LDS dest. No VGPR
//    staging -> compiler cannot collapse the pipeline (round-1 failure).
//  - 2-slot/wave staging, steady state 20 loads (5 KB) in flight per wave:
//    loop r: { s_waitcnt vmcnt(10); consume row r from slot r&1;
//              issue row r+2 into slot r&1 }. vmcnt decrement certifies the
//    async LDS write landed; consume's ds_reads are lgkm-consumed before the
//    slot is re-issued -> no WAR race. sched_barrier(0) pins issue order so
//    the manual vmcnt counts stay valid.
// Numerics identical to v1/v2 (same per-element FMA order) -> absmax same.
// LDS: 32 KB tile + 20 KB staging = 52 KB -> 3 blocks/CU.
// ---------------------------------------------------------------------------
template <bool SELF_F32, bool QOUT>
__global__ __launch_bounds__(256, 3) void sage_layer(
    const void*     __restrict__ hin_v,  // self table: f32 or bf16 [NN][D]
    const uint8_t*  __restrict__ qtab,   // gather table int8 [NN][D]
    const float*    __restrict__ qsc,    // [NN] gather row scales
    const int*      __restrict__ adj,    // [NN][NK]
    const uint16_t* __restrict__ Wp,     // packed bf16 W [16][16][64][8]
    const float*    __restrict__ bias,   // [D] f32
    void*           __restrict__ hout_v, // bf16 (QOUT) / f32 (!QOUT)
    uint8_t*        __restrict__ q8out,  // int8 table out (QOUT)
    float*          __restrict__ qsout)  // row scales out (QOUT)
{
  __shared__ uint4    lds4[MT * 64];            // 32 rows * 64 chunks * 16B
  __shared__ uint32_t stg[4 * 2 * NK * 64];     // 4 waves * 2 slots * 10 rows * 256B

  const int t  = threadIdx.x;
  const int m0 = blockIdx.x * MT;
  const int w  = t >> 6;                  // wave 0..3
  const int l  = t & 63;

  // ---- adj prefetch: wave's 8 rows = 80 indices in 2 coalesced loads ----
  const int* ap = adj + (size_t)(m0 + 8 * w) * NK;
  int av0 = ap[l];                        // j = 0..63
  int av1 = ap[64 + (l & 15)];            // j = 64..79 in lanes 0..15
  __builtin_amdgcn_sched_barrier(0);

  // ---- self-row loads: issue now, consumed after gather issue ----
  float4 sv[4][2];                        // SELF_F32 path
  uint4  sb[4];                           // bf16 path
#pragma unroll
  for (int i = 0; i < 4; i++) {
    int cidx = t + i * 256;
    int r = cidx >> 5, c = cidx & 31;
    if constexpr (SELF_F32) {
      const float4* p =
          (const float4*)((const float*)hin_v + (size_t)(m0 + r) * D + c * 8);
      sv[i][0] = p[0];
      sv[i][1] = p[1];
    } else {
      sb[i] = *(const uint4*)((const uint16_t*)hin_v + (size_t)(m0 + r) * D + c * 8);
    }
  }
  __builtin_amdgcn_sched_barrier(0);

  // ---- scale prefetch (stalls on av return; self loads already in flight) ----
  float sp0 = qsc[av0];
  float sp1 = qsc[av1];
  __builtin_amdgcn_sched_barrier(0);

  // ---- async gather issue: one global_load_lds per neighbor row ----
  auto issue_row = [&](int r) {
#pragma unroll
    for (int k = 0; k < NK; k++) {
      const int j = r * NK + k;
      int nb = (j < 64) ? __shfl(av0, j, 64) : __shfl(av1, j - 64, 64);
      gload_lds4(qtab + (size_t)nb * D + l * 4,
                 &stg[(((w << 1) | (r & 1)) * NK + k) * 64]);
    }
  };

  issue_row(0);
  issue_row(1);
  __builtin_amdgcn_sched_barrier(0);

  // ---- self rows -> tile chunks 0..31 (overlaps gather flight) ----
#pragma unroll
  for (int i = 0; i < 4; i++) {
    int cidx = t + i * 256;
    int r = cidx >> 5, c = cidx & 31;
    uint4 o;
    if constexpr (SELF_F32) {
      o.x = pack2(sv[i][0].x, sv[i][0].y);
      o.y = pack2(sv[i][0].z, sv[i][0].w);
      o.z = pack2(sv[i][1].x, sv[i][1].y);
      o.w = pack2(sv[i][1].z, sv[i][1].w);
    } else {
      o = sb[i];
    }
    lds4[r * 64 + (c ^ (r & 15))] = o;
  }
  __builtin_amdgcn_sched_barrier(0);

  // ---- pipelined consume: row r from slot r&1, then issue row r+2 ----
  const float scK = 1.0f / (float)NK;
#pragma unroll
  for (int r = 0; r < 8; r++) {
    if (r < 7) asm volatile("s_waitcnt vmcnt(10)" ::: "memory");
    else       asm volatile("s_waitcnt vmcnt(0)"  ::: "memory");
    __builtin_amdgcn_sched_barrier(0);

    float c0 = 0.f, c1 = 0.f, c2 = 0.f, c3 = 0.f;
#pragma unroll
    for (int k = 0; k < NK; k++) {
      const int j = r * NK + k;
      float s = (j < 64) ? __shfl(sp0, j, 64) : __shfl(sp1, j - 64, 64);
      uint32_t v = stg[(((w << 1) | (r & 1)) * NK + k) * 64 + l];
      c0 += s * (float)(int8_t)(v);
      c1 += s * (float)(int8_t)(v >> 8);
      c2 += s * (float)(int8_t)(v >> 16);
      c3 += s * (float)(int8_t)(v >> 24);
    }
    // lane l covers gather elems 4l..4l+3 -> concat k = 256+4l
    uint2 o;
    o.x = pack2(c0 * scK, c1 * scK);
    o.y = pack2(c2 * scK, c3 * scK);
    const int r8 = 8 * w + r;
    const int cc = 32 + (l >> 1);
    *(uint2*)((uint8_t*)lds4 +
              ((r8 * 64 + (cc ^ (r8 & 15))) * 16 + (l & 1) * 8)) = o;
    __builtin_amdgcn_sched_barrier(0);
    if (r < 6) issue_row(r + 2);
    __builtin_amdgcn_sched_barrier(0);
  }

  __syncthreads();

  // ---- GEMM  [32 x 512] @ [512 x 256] ----
  const int quad = l >> 4;
  const int l16  = l & 15;

  f32x4 acc[2][4];
#pragma unroll
  for (int mt = 0; mt < 2; mt++)
#pragma unroll
    for (int nt = 0; nt < 4; nt++)
      acc[mt][nt] = (f32x4){0.f, 0.f, 0.f, 0.f};

  const uint4* wp4 = (const uint4*)Wp;

#pragma unroll 2
  for (int ks = 0; ks < 16; ks++) {
    bf16x8 af[2], bfr[4];
#pragma unroll
    for (int mt = 0; mt < 2; mt++) {
      int row = mt * 16 + l16;                 // A: m = lane&15
      int c   = ks * 4 + quad;                 // A: k = quad*8 + j
      af[mt] = *((const bf16x8*)&lds4[row * 64 + (c ^ (row & 15))]);
    }
#pragma unroll
    for (int nt = 0; nt < 4; nt++) {
      bfr[nt] = *((const bf16x8*)&wp4[(ks * 16 + (w * 4 + nt)) * 64 + l]);
    }
#pragma unroll
    for (int mt = 0; mt < 2; mt++)
#pragma unroll
      for (int nt = 0; nt < 4; nt++)
        acc[mt][nt] = __builtin_amdgcn_mfma_f32_16x16x32_bf16(
            af[mt], bfr[nt], acc[mt][nt], 0, 0, 0);
  }

  // ---- epilogue: bias (+ReLU), row-scale quant (QOUT), store ----
  float lmax[2][4];
#pragma unroll
  for (int mt = 0; mt < 2; mt++)
#pragma unroll
    for (int i = 0; i < 4; i++) lmax[mt][i] = 0.0f;

#pragma unroll
  for (int mt = 0; mt < 2; mt++)
#pragma unroll
    for (int nt = 0; nt < 4; nt++)
#pragma unroll
      for (int i = 0; i < 4; i++) {
        int col = w * 64 + nt * 16 + l16;      // C/D: col = lane&15
        float v = acc[mt][nt][i] + bias[col];
        if (QOUT) v = fmaxf(v, 0.0f);          // ReLU on layers 0,1
        acc[mt][nt][i] = v;
        if (QOUT) lmax[mt][i] = fmaxf(lmax[mt][i], v);
      }

  float inv[2][4];
  if (QOUT) {
    // reduce rowmax across the 16 lanes of each quad-group
#pragma unroll
    for (int d = 1; d < 16; d <<= 1)
#pragma unroll
      for (int mt = 0; mt < 2; mt++)
#pragma unroll
        for (int i = 0; i < 4; i++)
          lmax[mt][i] = fmaxf(lmax[mt][i], __shfl_xor(lmax[mt][i], d, 64));
    __syncthreads();                            // lds4 dead -> reuse for rowmax
    float* rmax = (float*)lds4;                 // [32 rows][4 waves]
    if (l16 == 0) {
#pragma unroll
      for (int mt = 0; mt < 2; mt++)
#pragma unroll
        for (int i = 0; i < 4; i++)
          rmax[(mt * 16 + quad * 4 + i) * 4 + w] = lmax[mt][i];
    }
    __syncthreads();
#pragma unroll
    for (int mt = 0; mt < 2; mt++)
#pragma unroll
      for (int i = 0; i < 4; i++) {
        int row = mt * 16 + quad * 4 + i;
        float m = fmaxf(fmaxf(rmax[row * 4 + 0], rmax[row * 4 + 1]),
                        fmaxf(rmax[row * 4 + 2], rmax[row * 4 + 3]));
        inv[mt][i] = m > 1e-30f ? 127.0f / m : 0.0f;
        if (w == 0 && l16 == 0) qsout[m0 + row] = m * (1.0f / 127.0f);
      }
  }

#pragma unroll
  for (int mt = 0; mt < 2; mt++)
#pragma unroll
    for (int i = 0; i < 4; i++) {
      int rr = m0 + mt * 16 + quad * 4 + i;     // C/D: row = quad*4 + reg
#pragma unroll
      for (int nt = 0; nt < 4; nt++) {
        int col = w * 64 + nt * 16 + l16;
        float v = acc[mt][nt][i];
        if (QOUT) {
          ((uint16_t*)hout_v)[(size_t)rr * D + col] = f2bf(v);
          int q = (int)rintf(v * inv[mt][i]);
          q8out[(size_t)rr * D + col] = (uint8_t)(q & 0xff);
        } else {
          ((float*)hout_v)[(size_t)rr * D + col] = v;
        }
      }
    }
}

extern "C" void kernel_launch(void* const* d_in, const int* in_sizes, int n_in,
                              void* d_out, int out_size, void* d_ws, size_t ws_size,
                              hipStream_t stream) {
  const float* x   = (const float*)d_in[0];
  const int*   adj = (const int*)d_in[1];
  const float* W0  = (const float*)d_in[2];
  const float* b0  = (const float*)d_in[3];
  const float* W1  = (const float*)d_in[4];
  const float* b1  = (const float*)d_in[5];
  const float* W2  = (const float*)d_in[6];
  const float* b2  = (const float*)d_in[7];
  float* out = (float*)d_out;

  // d_out doubles as scratch until layer 2 overwrites it (102.4 MB exactly):
  //   hA  bf16 [NN][D] : bytes [0, 51.2e6)          written L0, read L1
  //   hA8 int8 [NN][D] : bytes [51.2e6, 76.8e6)     written L0, read L1
  //   x8  int8 [NN][D] : bytes [76.8e6, 102.4e6)    written prep, read L0
  uint8_t*  dob = (uint8_t*)d_out;
  uint16_t* hA  = (uint16_t*)dob;
  uint8_t*  hA8 = dob + 51200000;
  uint8_t*  x8  = dob + 76800000;

  // ws (~78.8 MB): Wp x3 + hB + hB8 + scales
  uint16_t* ws  = (uint16_t*)d_ws;
  uint16_t* Wp0 = ws;
  uint16_t* Wp1 = Wp0 + D2 * D;
  uint16_t* Wp2 = Wp1 + D2 * D;
  uint16_t* hB  = Wp2 + D2 * D;                      // bf16 [NN][D]
  uint8_t*  hB8 = (uint8_t*)(hB + (size_t)NN * D);   // int8 [NN][D]
  float*    xs  = (float*)(hB8 + (size_t)NN * D);    // [NN]
  float*    hAs = xs + NN;
  float*    hBs = hAs + NN;

  prep<<<192 + NN / 4, 256, 0, stream>>>(x, x8, xs, W0, W1, W2, Wp0, Wp1, Wp2);

  const int grid = NN / MT;              // 3125 blocks, exact
  sage_layer<true,  true ><<<grid, 256, 0, stream>>>(x,  x8,  xs,  adj, Wp0, b0, hA,  hA8, hAs);
  sage_layer<false, true ><<<grid, 256, 0, stream>>>(hA, hA8, hAs, adj, Wp1, b1, hB,  hB8, hBs);
  sage_layer<false, false><<<grid, 256, 0, stream>>>(hB, hB8, hBs, adj, Wp2, b2, out, nullptr, nullptr);
}

// Round 4
// 430.577 us; speedup vs baseline: 1.1431x; 1.1431x over previous
//
#include <hip/hip_runtime.h>
#include <stdint.h>

#define NN 100000   // nodes
#define NK 10       // sampled neighbors
#define D  256      // hidden dim
#define D2 512      // concat dim
#define MT 32       // nodes per block; 100000/32 = 3125 exactly -> no tails

typedef short bf16x8 __attribute__((ext_vector_type(8)));   // 8 bf16 (4 VGPRs)
typedef float f32x4  __attribute__((ext_vector_type(4)));
// clang ext-vector types for __builtin_nontemporal_* (HIP_vector_type rejected)
typedef float        vf4 __attribute__((ext_vector_type(4)));
typedef unsigned int vu4 __attribute__((ext_vector_type(4)));

__device__ __forceinline__ uint16_t f2bf(float f) {
  uint32_t u = __float_as_uint(f);
  u += 0x7fffu + ((u >> 16) & 1u);   // round-to-nearest-even
  return (uint16_t)(u >> 16);
}
__device__ __forceinline__ uint32_t pack2(float a, float b) {
  return (uint32_t)f2bf(a) | ((uint32_t)f2bf(b) << 16);
}

// ---------------------------------------------------------------------------
// prep: fused {3x pack_w , quant_x} in one launch.
// blocks [0,192): pack W0/W1/W2 into bf16 MFMA B-fragment order.
// blocks [192, 192+NN/4): int8-quantize x rows (one wave per row).
// x is single-use -> nt load; x8/qs are next-kernel gather tables -> normal.
// ---------------------------------------------------------------------------
__global__ __launch_bounds__(256) void prep(
    const float* __restrict__ x, uint8_t* __restrict__ q8, float* __restrict__ qs,
    const float* __restrict__ W0, const float* __restrict__ W1,
    const float* __restrict__ W2, uint16_t* __restrict__ Wp0,
    uint16_t* __restrict__ Wp1, uint16_t* __restrict__ Wp2)
{
  const int bid = blockIdx.x;
  if (bid < 192) {
    const float* W;
    uint16_t* Wp;
    if (bid < 64)       { W = W0; Wp = Wp0; }
    else if (bid < 128) { W = W1; Wp = Wp1; }
    else                { W = W2; Wp = Wp2; }
    int idx   = ((bid & 63) << 8) + threadIdx.x;   // 0..16383
    int lane  = idx & 63;
    int ntile = (idx >> 6) & 15;
    int kstep = idx >> 10;
    int n  = ntile * 16 + (lane & 15);
    int k0 = kstep * 32 + (lane >> 4) * 8;
    float v[8];
#pragma unroll
    for (int j = 0; j < 8; j++) v[j] = W[(size_t)(k0 + j) * D + n];
    uint4 o;
    o.x = pack2(v[0], v[1]);
    o.y = pack2(v[2], v[3]);
    o.z = pack2(v[4], v[5]);
    o.w = pack2(v[6], v[7]);
    ((uint4*)Wp)[idx] = o;
  } else {
    int node = (bid - 192) * 4 + (threadIdx.x >> 6);
    int lane = threadIdx.x & 63;
    const vf4 v = __builtin_nontemporal_load(
        (const vf4*)(x + (size_t)node * D + lane * 4));
    float m = fmaxf(fmaxf(fabsf(v.x), fabsf(v.y)), fmaxf(fabsf(v.z), fabsf(v.w)));
#pragma unroll
    for (int d = 1; d < 64; d <<= 1) m = fmaxf(m, __shfl_xor(m, d, 64));
    float inv = m > 1e-30f ? 127.0f / m : 0.0f;
    int q0 = (int)rintf(v.x * inv), q1 = (int)rintf(v.y * inv);
    int q2 = (int)rintf(v.z * inv), q3 = (int)rintf(v.w * inv);
    uint32_t p = (uint32_t)(q0 & 0xff) | ((uint32_t)(q1 & 0xff) << 8) |
                 ((uint32_t)(q2 & 0xff) << 16) | ((uint32_t)(q3 & 0xff) << 24);
    ((uint32_t*)(q8 + (size_t)node * D))[lane] = p;
    if (lane == 0) qs[node] = m * (1.0f / 127.0f);
  }
}

// ---------------------------------------------------------------------------
// Fused SAGE layer, v4 = v2 structure (best measured) + cache-traffic shaping:
//  - single-use streams (self rows in, hout out) use non-temporal load/store
//    so they stop evicting the int8 gather table from L2/L3. The table
//    (25.6 MB), adj (4 MB), qsc and Wp stay normally cached.
//  - q8out store is NORMAL on purpose: it is the next layer's gather table;
//    a normal store leaves it L3-resident for the next kernel's random reads.
//  - adj hoisted to wave start (4 coalesced loads, broadcast via __shfl).
// Numerics identical -> absmax unchanged.
// LDS: 32 rows x 512 k bf16 = 32 KB. XOR swizzle on 16B chunks (0 conflicts).
// ---------------------------------------------------------------------------
template <bool SELF_F32, bool QOUT>
__global__ __launch_bounds__(256, 4) void sage_layer(
    const void*     __restrict__ hin_v,  // self table: f32 or bf16 [NN][D]
    const uint8_t*  __restrict__ qtab,   // gather table int8 [NN][D]
    const float*    __restrict__ qsc,    // [NN] gather row scales
    const int*      __restrict__ adj,    // [NN][NK]
    const uint16_t* __restrict__ Wp,     // packed bf16 W [16][16][64][8]
    const float*    __restrict__ bias,   // [D] f32
    void*           __restrict__ hout_v, // bf16 (QOUT) / f32 (!QOUT)
    uint8_t*        __restrict__ q8out,  // int8 table out (QOUT)
    float*          __restrict__ qsout)  // row scales out (QOUT)
{
  __shared__ uint4 lds4[MT * 64];        // 32 rows * 64 chunks * 16B = 32 KB
  const int t    = threadIdx.x;
  const int m0   = blockIdx.x * MT;
  const int half = t >> 5;               // 0..7; wave w owns halves 2w, 2w+1
  const int l32  = t & 31;
  const int hb   = half & ~1;            // wave's row-pair base
  const int hsel = (half & 1) * 10;      // adj-entry offset for this half

  // ---- adj for this wave's 8 rows: 4 x 80B coalesced loads, issued first ----
  int av0, av1, av2, av3;
  {
    const int* ap = adj + (size_t)(m0 + hb) * NK;
    int o = (l32 < 20) ? l32 : 0;
    av0 = ap[o];
    av1 = ap[80 + o];
    av2 = ap[160 + o];
    av3 = ap[240 + o];
  }

  // gather staging (double-buffered; all indexing compile-time -> registers)
  uint2 gA[NK], gB[NK];
  float sA[NK], sB[NK];

  auto issue = [&](int av, uint2 (&g)[NK], float (&s)[NK]) {
#pragma unroll
    for (int k = 0; k < NK; k++) {
      int nb = __shfl(av, hsel + k, 32);     // broadcast within 32-lane half
      s[k] = qsc[nb];
      g[k] = *(const uint2*)(qtab + (size_t)nb * D + l32 * 8);
    }
  };
  auto consume = [&](const uint2 (&g)[NK], const float (&s)[NK], int i) {
    int r = i * 8 + half;
    float a0=0.f,a1=0.f,a2=0.f,a3=0.f,a4=0.f,a5=0.f,a6=0.f,a7=0.f;
#pragma unroll
    for (int k = 0; k < NK; k++) {
      float sk = s[k];
      uint2 v  = g[k];
      a0 += sk * (float)(int8_t)(v.x);
      a1 += sk * (float)(int8_t)(v.x >> 8);
      a2 += sk * (float)(int8_t)(v.x >> 16);
      a3 += sk * (float)(int8_t)(v.x >> 24);
      a4 += sk * (float)(int8_t)(v.y);
      a5 += sk * (float)(int8_t)(v.y >> 8);
      a6 += sk * (float)(int8_t)(v.y >> 16);
      a7 += sk * (float)(int8_t)(v.y >> 24);
    }
    const float sc = 1.0f / (float)NK;
    uint4 o;
    o.x = pack2(a0 * sc, a1 * sc);
    o.y = pack2(a2 * sc, a3 * sc);
    o.z = pack2(a4 * sc, a5 * sc);
    o.w = pack2(a6 * sc, a7 * sc);
    int c = 32 + l32;
    lds4[r * 64 + (c ^ (r & 15))] = o;
  };

  // ---- phase 1 (self rows -> chunks 0..31) interleaved with gather issue ----
  if constexpr (SELF_F32) {
#pragma unroll
    for (int i = 0; i < 4; i++) {
      int cidx = t + i * 256;
      int r = cidx >> 5, c = cidx & 31;
      const vf4* p =
          (const vf4*)((const float*)hin_v + (size_t)(m0 + r) * D + c * 8);
      vf4 v0 = __builtin_nontemporal_load(p);
      vf4 v1 = __builtin_nontemporal_load(p + 1);
      uint4 o;
      o.x = pack2(v0.x, v0.y); o.y = pack2(v0.z, v0.w);
      o.z = pack2(v1.x, v1.y); o.w = pack2(v1.z, v1.w);
      lds4[r * 64 + (c ^ (r & 15))] = o;
    }
    issue(av0, gA, sA);
    issue(av1, gB, sB);
  } else {
    // bf16 layers: load self rows to regs, start gather, then LDS-write
    vu4 p1[4];
#pragma unroll
    for (int i = 0; i < 4; i++) {
      int cidx = t + i * 256;
      int r = cidx >> 5, c = cidx & 31;
      p1[i] = __builtin_nontemporal_load(
          (const vu4*)((const uint16_t*)hin_v + (size_t)(m0 + r) * D + c * 8));
    }
    issue(av0, gA, sA);
    issue(av1, gB, sB);
#pragma unroll
    for (int i = 0; i < 4; i++) {
      int cidx = t + i * 256;
      int r = cidx >> 5, c = cidx & 31;
      *(vu4*)&lds4[r * 64 + (c ^ (r & 15))] = p1[i];
    }
  }

  // ---- phase 2: 2-deep pipelined gather-mean -> chunks 32..63 ----
  consume(gA, sA, 0);
  issue(av2, gA, sA);
  consume(gB, sB, 1);
  issue(av3, gB, sB);
  consume(gA, sA, 2);
  consume(gB, sB, 3);

  __syncthreads();

  // ---- phase 3: GEMM  [32 x 512] @ [512 x 256] ----
  const int w    = t >> 6;   // wave 0..3 -> output cols w*64 .. w*64+63
  const int l    = t & 63;
  const int quad = l >> 4;
  const int l16  = l & 15;

  f32x4 acc[2][4];
#pragma unroll
  for (int mt = 0; mt < 2; mt++)
#pragma unroll
    for (int nt = 0; nt < 4; nt++)
      acc[mt][nt] = (f32x4){0.f, 0.f, 0.f, 0.f};

  const uint4* wp4 = (const uint4*)Wp;

#pragma unroll 2
  for (int ks = 0; ks < 16; ks++) {
    bf16x8 af[2], bfr[4];
#pragma unroll
    for (int mt = 0; mt < 2; mt++) {
      int row = mt * 16 + l16;                 // A: m = lane&15
      int c   = ks * 4 + quad;                 // A: k = quad*8 + j
      af[mt] = *((const bf16x8*)&lds4[row * 64 + (c ^ (row & 15))]);
    }
#pragma unroll
    for (int nt = 0; nt < 4; nt++) {
      bfr[nt] = *((const bf16x8*)&wp4[(ks * 16 + (w * 4 + nt)) * 64 + l]);
    }
#pragma unroll
    for (int mt = 0; mt < 2; mt++)
#pragma unroll
      for (int nt = 0; nt < 4; nt++)
        acc[mt][nt] = __builtin_amdgcn_mfma_f32_16x16x32_bf16(
            af[mt], bfr[nt], acc[mt][nt], 0, 0, 0);
  }

  // ---- epilogue: bias (+ReLU), row-scale quant (QOUT), store ----
  float lmax[2][4];
#pragma unroll
  for (int mt = 0; mt < 2; mt++)
#pragma unroll
    for (int i = 0; i < 4; i++) lmax[mt][i] = 0.0f;

#pragma unroll
  for (int mt = 0; mt < 2; mt++)
#pragma unroll
    for (int nt = 0; nt < 4; nt++)
#pragma unroll
      for (int i = 0; i < 4; i++) {
        int col = w * 64 + nt * 16 + l16;      // C/D: col = lane&15
        float v = acc[mt][nt][i] + bias[col];
        if (QOUT) v = fmaxf(v, 0.0f);          // ReLU on layers 0,1
        acc[mt][nt][i] = v;
        if (QOUT) lmax[mt][i] = fmaxf(lmax[mt][i], v);
      }

  float inv[2][4];
  if (QOUT) {
    // reduce rowmax across the 16 lanes of each quad-group
#pragma unroll
    for (int d = 1; d < 16; d <<= 1)
#pragma unroll
      for (int mt = 0; mt < 2; mt++)
#pragma unroll
        for (int i = 0; i < 4; i++)
          lmax[mt][i] = fmaxf(lmax[mt][i], __shfl_xor(lmax[mt][i], d, 64));
    __syncthreads();                            // lds4 dead -> reuse for rowmax
    float* rmax = (float*)lds4;                 // [32 rows][4 waves]
    if (l16 == 0) {
#pragma unroll
      for (int mt = 0; mt < 2; mt++)
#pragma unroll
        for (int i = 0; i < 4; i++)
          rmax[(mt * 16 + quad * 4 + i) * 4 + w] = lmax[mt][i];
    }
    __syncthreads();
#pragma unroll
    for (int mt = 0; mt < 2; mt++)
#pragma unroll
      for (int i = 0; i < 4; i++) {
        int row = mt * 16 + quad * 4 + i;
        float m = fmaxf(fmaxf(rmax[row * 4 + 0], rmax[row * 4 + 1]),
                        fmaxf(rmax[row * 4 + 2], rmax[row * 4 + 3]));
        inv[mt][i] = m > 1e-30f ? 127.0f / m : 0.0f;
        if (w == 0 && l16 == 0) qsout[m0 + row] = m * (1.0f / 127.0f);
      }
  }

#pragma unroll
  for (int mt = 0; mt < 2; mt++)
#pragma unroll
    for (int i = 0; i < 4; i++) {
      int rr = m0 + mt * 16 + quad * 4 + i;     // C/D: row = quad*4 + reg
#pragma unroll
      for (int nt = 0; nt < 4; nt++) {
        int col = w * 64 + nt * 16 + l16;
        float v = acc[mt][nt][i];
        if (QOUT) {
          // hout (bf16 self table) is streamed once next layer -> nt store.
          __builtin_nontemporal_store(
              f2bf(v), (uint16_t*)hout_v + (size_t)rr * D + col);
          // q8out is the NEXT layer's gather table -> normal store (stay in L3)
          int q = (int)rintf(v * inv[mt][i]);
          q8out[(size_t)rr * D + col] = (uint8_t)(q & 0xff);
        } else {
          __builtin_nontemporal_store(v, (float*)hout_v + (size_t)rr * D + col);
        }
      }
    }
}

extern "C" void kernel_launch(void* const* d_in, const int* in_sizes, int n_in,
                              void* d_out, int out_size, void* d_ws, size_t ws_size,
                              hipStream_t stream) {
  const float* x   = (const float*)d_in[0];
  const int*   adj = (const int*)d_in[1];
  const float* W0  = (const float*)d_in[2];
  const float* b0  = (const float*)d_in[3];
  const float* W1  = (const float*)d_in[4];
  const float* b1  = (const float*)d_in[5];
  const float* W2  = (const float*)d_in[6];
  const float* b2  = (const float*)d_in[7];
  float* out = (float*)d_out;

  // d_out doubles as scratch until layer 2 overwrites it (102.4 MB exactly):
  //   hA  bf16 [NN][D] : bytes [0, 51.2e6)          written L0, read L1
  //   hA8 int8 [NN][D] : bytes [51.2e6, 76.8e6)     written L0, read L1
  //   x8  int8 [NN][D] : bytes [76.8e6, 102.4e6)    written prep, read L0
  uint8_t*  dob = (uint8_t*)d_out;
  uint16_t* hA  = (uint16_t*)dob;
  uint8_t*  hA8 = dob + 51200000;
  uint8_t*  x8  = dob + 76800000;

  // ws (~78.8 MB): Wp x3 + hB + hB8 + scales
  uint16_t* ws  = (uint16_t*)d_ws;
  uint16_t* Wp0 = ws;
  uint16_t* Wp1 = Wp0 + D2 * D;
  uint16_t* Wp2 = Wp1 + D2 * D;
  uint16_t* hB  = Wp2 + D2 * D;                      // bf16 [NN][D]
  uint8_t*  hB8 = (uint8_t*)(hB + (size_t)NN * D);   // int8 [NN][D]
  float*    xs  = (float*)(hB8 + (size_t)NN * D);    // [NN]
  float*    hAs = xs + NN;
  float*    hBs = hAs + NN;

  prep<<<192 + NN / 4, 256, 0, stream>>>(x, x8, xs, W0, W1, W2, Wp0, Wp1, Wp2);

  const int grid = NN / MT;              // 3125 blocks, exact
  sage_layer<true,  true ><<<grid, 256, 0, stream>>>(x,  x8,  xs,  adj, Wp0, b0, hA,  hA8, hAs);
  sage_layer<false, true ><<<grid, 256, 0, stream>>>(hA, hA8, hAs, adj, Wp1, b1, hB,  hB8, hBs);
  sage_layer<false, false><<<grid, 256, 0, stream>>>(hB, hB8, hBs, adj, Wp2, b2, out, nullptr, nullptr);
}

// Round 6
// 424.253 us; speedup vs baseline: 1.1601x; 1.0149x over previous
//
#include <hip/hip_runtime.h>
#include <stdint.h>

#define NN 100000   // nodes
#define NK 10       // sampled neighbors
#define D  256      // hidden dim
#define D2 512      // concat dim
#define MT 32       // nodes per block; 100000/32 = 3125 exactly -> no tails

typedef short bf16x8 __attribute__((ext_vector_type(8)));   // 8 bf16 (4 VGPRs)
typedef float f32x4  __attribute__((ext_vector_type(4)));
typedef unsigned int vu2a __attribute__((ext_vector_type(2)));
typedef unsigned int vu4a __attribute__((ext_vector_type(4)));
typedef float        vf4  __attribute__((ext_vector_type(4)));

__device__ __forceinline__ uint16_t f2bf(float f) {
  uint32_t u = __float_as_uint(f);
  u += 0x7fffu + ((u >> 16) & 1u);   // round-to-nearest-even
  return (uint16_t)(u >> 16);
}
__device__ __forceinline__ uint32_t pack2(float a, float b) {
  return (uint32_t)f2bf(a) | ((uint32_t)f2bf(b) << 16);
}

// Inline-asm global loads: explicit "=v" destinations the compiler cannot
// sink/collapse; volatile asm order is program order, so manual vmcnt
// counting is exact (as long as no compiler VMEM interleaves -> keep peak
// VGPR well under the cap so no scratch spills appear in the prologue).
__device__ __forceinline__ void gl_f32(float &d, uint64_t a) {
  asm volatile("global_load_dword %0, %1, off" : "=v"(d) : "v"(a));
}
__device__ __forceinline__ void gl_b64(vu2a &d, uint64_t a) {
  asm volatile("global_load_dwordx2 %0, %1, off" : "=v"(d) : "v"(a));
}
__device__ __forceinline__ void gl_b128(vu4a &d, uint64_t a) {
  asm volatile("global_load_dwordx4 %0, %1, off" : "=v"(d) : "v"(a));
}
// counted wait + scheduler fence
#define VMWAIT(N)                                            \
  do {                                                       \
    asm volatile("s_waitcnt vmcnt(" #N ")" ::: "memory");    \
    __builtin_amdgcn_sched_barrier(0);                       \
  } while (0)
// dependency anchors: volatile identity-asm pins the first USE of an
// asm-loaded register after the waitcnt (volatile-asm mutual order +
// data dependency). Zero instructions emitted.
__device__ __forceinline__ void vsync_i(int &x)    { asm volatile("" : "+v"(x)); }
__device__ __forceinline__ void vsync_f(float &x)  { asm volatile("" : "+v"(x)); }
__device__ __forceinline__ void vsync_u2(vu2a &x)  { asm volatile("" : "+v"(x)); }
__device__ __forceinline__ void vsync_u4(vu4a &x)  { asm volatile("" : "+v"(x)); }

// ---------------------------------------------------------------------------
// prep: fused {3x pack_w , quant_x} in one launch.
// ---------------------------------------------------------------------------
__global__ __launch_bounds__(256) void prep(
    const float* __restrict__ x, uint8_t* __restrict__ q8, float* __restrict__ qs,
    const float* __restrict__ W0, const float* __restrict__ W1,
    const float* __restrict__ W2, uint16_t* __restrict__ Wp0,
    uint16_t* __restrict__ Wp1, uint16_t* __restrict__ Wp2)
{
  const int bid = blockIdx.x;
  if (bid < 192) {
    const float* W;
    uint16_t* Wp;
    if (bid < 64)       { W = W0; Wp = Wp0; }
    else if (bid < 128) { W = W1; Wp = Wp1; }
    else                { W = W2; Wp = Wp2; }
    int idx   = ((bid & 63) << 8) + threadIdx.x;   // 0..16383
    int lane  = idx & 63;
    int ntile = (idx >> 6) & 15;
    int kstep = idx >> 10;
    int n  = ntile * 16 + (lane & 15);
    int k0 = kstep * 32 + (lane >> 4) * 8;
    float v[8];
#pragma unroll
    for (int j = 0; j < 8; j++) v[j] = W[(size_t)(k0 + j) * D + n];
    uint4 o;
    o.x = pack2(v[0], v[1]);
    o.y = pack2(v[2], v[3]);
    o.z = pack2(v[4], v[5]);
    o.w = pack2(v[6], v[7]);
    ((uint4*)Wp)[idx] = o;
  } else {
    int node = (bid - 192) * 4 + (threadIdx.x >> 6);
    int lane = threadIdx.x & 63;
    const vf4 v = *(const vf4*)(x + (size_t)node * D + lane * 4);
    float m = fmaxf(fmaxf(fabsf(v.x), fabsf(v.y)), fmaxf(fabsf(v.z), fabsf(v.w)));
#pragma unroll
    for (int d = 1; d < 64; d <<= 1) m = fmaxf(m, __shfl_xor(m, d, 64));
    float inv = m > 1e-30f ? 127.0f / m : 0.0f;
    int q0 = (int)rintf(v.x * inv), q1 = (int)rintf(v.y * inv);
    int q2 = (int)rintf(v.z * inv), q3 = (int)rintf(v.w * inv);
    uint32_t p = (uint32_t)(q0 & 0xff) | ((uint32_t)(q1 & 0xff) << 8) |
                 ((uint32_t)(q2 & 0xff) << 16) | ((uint32_t)(q3 & 0xff) << 24);
    ((uint32_t*)(q8 + (size_t)node * D))[lane] = p;
    if (lane == 0) qs[node] = m * (1.0f / 127.0f);
  }
}

// ---------------------------------------------------------------------------
// Fused SAGE layer, v6: ASM-ENFORCED gather pipeline (register staging),
// hardened vs v5:
//  - dependency anchors (vsync_*) after every VMWAIT so no consumer of an
//    asm-loaded register can be scheduled above its waitcnt (wild-address
//    fault / junk-data hazard).
//  - self rows LDS-written BEFORE the second gather issue -> peak staged
//    VGPRs ~62 (spill-free prologue; spills would corrupt vmcnt counts).
// Schedule per wave (out = outstanding vmem ops):
//   adj4, selfN -> w(adj) -> issue0 -> w(self) -> self_to_lds -> issue1
//   -> w(20) c0, issue2 -> w(20) c1, issue3 -> w(20) c2 -> w(0) c3.
// Steady state 20-40 loads in flight per wave. Numerics identical.
// LDS: 32 rows x 512 k bf16 = 32 KB. XOR swizzle on 16B chunks (0 conflicts).
// ---------------------------------------------------------------------------
template <bool SELF_F32, bool QOUT>
__global__ __launch_bounds__(256, 4) void sage_layer(
    const void*     __restrict__ hin_v,  // self table: f32 or bf16 [NN][D]
    const uint8_t*  __restrict__ qtab,   // gather table int8 [NN][D]
    const float*    __restrict__ qsc,    // [NN] gather row scales
    const int*      __restrict__ adj,    // [NN][NK]
    const uint16_t* __restrict__ Wp,     // packed bf16 W [16][16][64][8]
    const float*    __restrict__ bias,   // [D] f32
    void*           __restrict__ hout_v, // bf16 (QOUT) / f32 (!QOUT)
    uint8_t*        __restrict__ q8out,  // int8 table out (QOUT)
    float*          __restrict__ qsout)  // row scales out (QOUT)
{
  __shared__ uint4 lds4[MT * 64];        // 32 rows * 64 chunks * 16B = 32 KB
  const int t    = threadIdx.x;
  const int m0   = blockIdx.x * MT;
  const int half = t >> 5;               // 0..7; wave w owns halves 2w, 2w+1
  const int l32  = t & 31;
  const int hb   = half & ~1;            // wave's row-pair base
  const int hsel = (half & 1) * 10;      // adj-entry offset for this half

  // ---- adj: 4 x 80B coalesced asm loads (8 rows each) ----
  int av0, av1, av2, av3;
  {
    int o = (l32 < 20) ? l32 : 0;
    uint64_t aa = (uint64_t)(adj + (size_t)(m0 + hb) * NK + o);
    asm volatile("global_load_dword %0, %1, off"            : "=v"(av0) : "v"(aa));
    asm volatile("global_load_dword %0, %1, off offset:320" : "=v"(av1) : "v"(aa));
    asm volatile("global_load_dword %0, %1, off offset:640" : "=v"(av2) : "v"(aa));
    asm volatile("global_load_dword %0, %1, off offset:960" : "=v"(av3) : "v"(aa));
  }

  // ---- self rows: asm loads issued now, LDS-written after adj+self wait ----
  vu4a p1[4];      // bf16 path: 4 x 16B
  vu4a pf[8];      // f32 path:  8 x 16B
#pragma unroll
  for (int i = 0; i < 4; i++) {
    int cidx = t + i * 256;
    int r = cidx >> 5, c = cidx & 31;
    if constexpr (SELF_F32) {
      uint64_t a = (uint64_t)((const float*)hin_v + (size_t)(m0 + r) * D + c * 8);
      gl_b128(pf[2 * i], a);
      gl_b128(pf[2 * i + 1], a + 16);
    } else {
      uint64_t a = (uint64_t)((const uint16_t*)hin_v + (size_t)(m0 + r) * D + c * 8);
      gl_b128(p1[i], a);
    }
  }

  // gather staging, double-buffered in explicitly-materialized registers
  vu2a gA[NK], gB[NK];
  float sA[NK], sB[NK];

  auto issue = [&](int av, vu2a (&g)[NK], float (&s)[NK]) {
#pragma unroll
    for (int k = 0; k < NK; k++) {
      int nb = __shfl(av, hsel + k, 32);     // broadcast within 32-lane half
      gl_f32(s[k], (uint64_t)(qsc + nb));
      gl_b64(g[k], (uint64_t)(qtab + (size_t)nb * D + l32 * 8));
    }
  };
  auto sync_buf = [&](vu2a (&g)[NK], float (&s)[NK]) {
#pragma unroll
    for (int k = 0; k < NK; k++) { vsync_u2(g[k]); vsync_f(s[k]); }
  };
  auto consume = [&](const vu2a (&g)[NK], const float (&s)[NK], int i) {
    int r = i * 8 + half;
    float a0=0.f,a1=0.f,a2=0.f,a3=0.f,a4=0.f,a5=0.f,a6=0.f,a7=0.f;
#pragma unroll
    for (int k = 0; k < NK; k++) {
      float sk = s[k];
      vu2a v  = g[k];
      a0 += sk * (float)(int8_t)(v.x);
      a1 += sk * (float)(int8_t)(v.x >> 8);
      a2 += sk * (float)(int8_t)(v.x >> 16);
      a3 += sk * (float)(int8_t)(v.x >> 24);
      a4 += sk * (float)(int8_t)(v.y);
      a5 += sk * (float)(int8_t)(v.y >> 8);
      a6 += sk * (float)(int8_t)(v.y >> 16);
      a7 += sk * (float)(int8_t)(v.y >> 24);
    }
    const float sc = 1.0f / (float)NK;
    uint4 o;
    o.x = pack2(a0 * sc, a1 * sc);
    o.y = pack2(a2 * sc, a3 * sc);
    o.z = pack2(a4 * sc, a5 * sc);
    o.w = pack2(a6 * sc, a7 * sc);
    int c = 32 + l32;
    lds4[r * 64 + (c ^ (r & 15))] = o;
  };

  auto self_to_lds = [&]() {
#pragma unroll
    for (int i = 0; i < 4; i++) {
      int cidx = t + i * 256;
      int r = cidx >> 5, c = cidx & 31;
      uint4 o;
      if constexpr (SELF_F32) {
        vu4a v0 = pf[2 * i], v1 = pf[2 * i + 1];
        o.x = pack2(__uint_as_float(v0.x), __uint_as_float(v0.y));
        o.y = pack2(__uint_as_float(v0.z), __uint_as_float(v0.w));
        o.z = pack2(__uint_as_float(v1.x), __uint_as_float(v1.y));
        o.w = pack2(__uint_as_float(v1.z), __uint_as_float(v1.w));
      } else {
        vu4a v = p1[i];
        o.x = v.x; o.y = v.y; o.z = v.z; o.w = v.w;
      }
      lds4[r * 64 + (c ^ (r & 15))] = o;
    }
  };

  if constexpr (SELF_F32) {
    // out: adj4 + self8 = 12
    VMWAIT(8);            // adj done, out 8
    vsync_i(av0); vsync_i(av1); vsync_i(av2); vsync_i(av3);
    issue(av0, gA, sA);   // out 28
    VMWAIT(20);           // self done, out 20
#pragma unroll
    for (int i = 0; i < 8; i++) vsync_u4(pf[i]);
    self_to_lds();        // frees pf (32 VGPRs) before second issue
    issue(av1, gB, sB);   // out 40
    VMWAIT(20);           // issue0 done, out 20
  } else {
    // out: adj4 + self4 = 8
    VMWAIT(4);            // adj done, out 4
    vsync_i(av0); vsync_i(av1); vsync_i(av2); vsync_i(av3);
    issue(av0, gA, sA);   // out 24
    VMWAIT(20);           // self done, out 20
#pragma unroll
    for (int i = 0; i < 4; i++) vsync_u4(p1[i]);
    self_to_lds();        // frees p1 (16 VGPRs) before second issue
    issue(av1, gB, sB);   // out 40
    VMWAIT(20);           // issue0 done, out 20
  }
  sync_buf(gA, sA);
  consume(gA, sA, 0);
  issue(av2, gA, sA);     // out 40
  VMWAIT(20);             // issue1 done, out 20
  sync_buf(gB, sB);
  consume(gB, sB, 1);
  issue(av3, gB, sB);     // out 40
  VMWAIT(20);             // issue2 done, out 20
  sync_buf(gA, sA);
  consume(gA, sA, 2);
  VMWAIT(0);              // issue3 done
  sync_buf(gB, sB);
  consume(gB, sB, 3);

  __syncthreads();

  // ---- GEMM  [32 x 512] @ [512 x 256] ----
  const int w    = t >> 6;   // wave 0..3 -> output cols w*64 .. w*64+63
  const int l    = t & 63;
  const int quad = l >> 4;
  const int l16  = l & 15;

  f32x4 acc[2][4];
#pragma unroll
  for (int mt = 0; mt < 2; mt++)
#pragma unroll
    for (int nt = 0; nt < 4; nt++)
      acc[mt][nt] = (f32x4){0.f, 0.f, 0.f, 0.f};

  const uint4* wp4 = (const uint4*)Wp;

#pragma unroll 2
  for (int ks = 0; ks < 16; ks++) {
    bf16x8 af[2], bfr[4];
#pragma unroll
    for (int mt = 0; mt < 2; mt++) {
      int row = mt * 16 + l16;                 // A: m = lane&15
      int c   = ks * 4 + quad;                 // A: k = quad*8 + j
      af[mt] = *((const bf16x8*)&lds4[row * 64 + (c ^ (row & 15))]);
    }
#pragma unroll
    for (int nt = 0; nt < 4; nt++) {
      bfr[nt] = *((const bf16x8*)&wp4[(ks * 16 + (w * 4 + nt)) * 64 + l]);
    }
#pragma unroll
    for (int mt = 0; mt < 2; mt++)
#pragma unroll
      for (int nt = 0; nt < 4; nt++)
        acc[mt][nt] = __builtin_amdgcn_mfma_f32_16x16x32_bf16(
            af[mt], bfr[nt], acc[mt][nt], 0, 0, 0);
  }

  // ---- epilogue: bias (+ReLU), row-scale quant (QOUT), store ----
  float lmax[2][4];
#pragma unroll
  for (int mt = 0; mt < 2; mt++)
#pragma unroll
    for (int i = 0; i < 4; i++) lmax[mt][i] = 0.0f;

#pragma unroll
  for (int mt = 0; mt < 2; mt++)
#pragma unroll
    for (int nt = 0; nt < 4; nt++)
#pragma unroll
      for (int i = 0; i < 4; i++) {
        int col = w * 64 + nt * 16 + l16;      // C/D: col = lane&15
        float v = acc[mt][nt][i] + bias[col];
        if (QOUT) v = fmaxf(v, 0.0f);          // ReLU on layers 0,1
        acc[mt][nt][i] = v;
        if (QOUT) lmax[mt][i] = fmaxf(lmax[mt][i], v);
      }

  float inv[2][4];
  if (QOUT) {
    // reduce rowmax across the 16 lanes of each quad-group
#pragma unroll
    for (int d = 1; d < 16; d <<= 1)
#pragma unroll
      for (int mt = 0; mt < 2; mt++)
#pragma unroll
        for (int i = 0; i < 4; i++)
          lmax[mt][i] = fmaxf(lmax[mt][i], __shfl_xor(lmax[mt][i], d, 64));
    __syncthreads();                            // lds4 dead -> reuse for rowmax
    float* rmax = (float*)lds4;                 // [32 rows][4 waves]
    if (l16 == 0) {
#pragma unroll
      for (int mt = 0; mt < 2; mt++)
#pragma unroll
        for (int i = 0; i < 4; i++)
          rmax[(mt * 16 + quad * 4 + i) * 4 + w] = lmax[mt][i];
    }
    __syncthreads();
#pragma unroll
    for (int mt = 0; mt < 2; mt++)
#pragma unroll
      for (int i = 0; i < 4; i++) {
        int row = mt * 16 + quad * 4 + i;
        float m = fmaxf(fmaxf(rmax[row * 4 + 0], rmax[row * 4 + 1]),
                        fmaxf(rmax[row * 4 + 2], rmax[row * 4 + 3]));
        inv[mt][i] = m > 1e-30f ? 127.0f / m : 0.0f;
        if (w == 0 && l16 == 0) qsout[m0 + row] = m * (1.0f / 127.0f);
      }
  }

#pragma unroll
  for (int mt = 0; mt < 2; mt++)
#pragma unroll
    for (int i = 0; i < 4; i++) {
      int rr = m0 + mt * 16 + quad * 4 + i;     // C/D: row = quad*4 + reg
#pragma unroll
      for (int nt = 0; nt < 4; nt++) {
        int col = w * 64 + nt * 16 + l16;
        float v = acc[mt][nt][i];
        if (QOUT) {
          ((uint16_t*)hout_v)[(size_t)rr * D + col] = f2bf(v);
          int q = (int)rintf(v * inv[mt][i]);
          q8out[(size_t)rr * D + col] = (uint8_t)(q & 0xff);
        } else {
          ((float*)hout_v)[(size_t)rr * D + col] = v;
        }
      }
    }
}

extern "C" void kernel_launch(void* const* d_in, const int* in_sizes, int n_in,
                              void* d_out, int out_size, void* d_ws, size_t ws_size,
                              hipStream_t stream) {
  const float* x   = (const float*)d_in[0];
  const int*   adj = (const int*)d_in[1];
  const float* W0  = (const float*)d_in[2];
  const float* b0  = (const float*)d_in[3];
  const float* W1  = (const float*)d_in[4];
  const float* b1  = (const float*)d_in[5];
  const float* W2  = (const float*)d_in[6];
  const float* b2  = (const float*)d_in[7];
  float* out = (float*)d_out;

  // d_out doubles as scratch until layer 2 overwrites it (102.4 MB exactly):
  //   hA  bf16 [NN][D] : bytes [0, 51.2e6)          written L0, read L1
  //   hA8 int8 [NN][D] : bytes [51.2e6, 76.8e6)     written L0, read L1
  //   x8  int8 [NN][D] : bytes [76.8e6, 102.4e6)    written prep, read L0
  uint8_t*  dob = (uint8_t*)d_out;
  uint16_t* hA  = (uint16_t*)dob;
  uint8_t*  hA8 = dob + 51200000;
  uint8_t*  x8  = dob + 76800000;

  // ws (~78.8 MB): Wp x3 + hB + hB8 + scales
  uint16_t* ws  = (uint16_t*)d_ws;
  uint16_t* Wp0 = ws;
  uint16_t* Wp1 = Wp0 + D2 * D;
  uint16_t* Wp2 = Wp1 + D2 * D;
  uint16_t* hB  = Wp2 + D2 * D;                      // bf16 [NN][D]
  uint8_t*  hB8 = (uint8_t*)(hB + (size_t)NN * D);   // int8 [NN][D]
  float*    xs  = (float*)(hB8 + (size_t)NN * D);    // [NN]
  float*    hAs = xs + NN;
  float*    hBs = hAs + NN;

  prep<<<192 + NN / 4, 256, 0, stream>>>(x, x8, xs, W0, W1, W2, Wp0, Wp1, Wp2);

  const int grid = NN / MT;              // 3125 blocks, exact
  sage_layer<true,  true ><<<grid, 256, 0, stream>>>(x,  x8,  xs,  adj, Wp0, b0, hA,  hA8, hAs);
  sage_layer<false, true ><<<grid, 256, 0, stream>>>(hA, hA8, hAs, adj, Wp1, b1, hB,  hB8, hBs);
  sage_layer<false, false><<<grid, 256, 0, stream>>>(hB, hB8, hBs, adj, Wp2, b2, out, nullptr, nullptr);
}